// Round 6
// baseline (101.340 us; speedup 1.0000x reference)
//
#include <hip/hip_runtime.h>
#include <math.h>

#define BEV_H 200
#define BEV_W 200
#define NPIX (BEV_H * BEV_W)
#define TILE 8
#define NT 25           // 200/8
#define NB 2
#define T_DEAD 1e-10f
#define MAXG 2048
#define KC 64
#define NLOG255 (-5.5412635f)   // -ln(255)

// Phase 1: per-gaussian screen params + conservative bbox, once per gaussian.
// params[g*2+0] = (u, v, qa, qb); params[g*2+1] = (qc, ln(op), 0, 0)
// alpha = op*exp(power) = exp(power + ln op); alpha>=1/255 <=> powb >= -ln255
__global__ __launch_bounds__(256) void precompute_kernel(
    const float* __restrict__ means3D, const float* __restrict__ cov3D,
    const float* __restrict__ opac, float4* __restrict__ params,
    float4* __restrict__ bbox, int n /* NB*G */)
{
    const int idx = blockIdx.x * 256 + threadIdx.x;
    if (idx >= n) return;
    const float x = means3D[idx * 3 + 0], y = means3D[idx * 3 + 1];
    const float sxx = cov3D[idx * 6 + 0], sxy = cov3D[idx * 6 + 1],
                syy = cov3D[idx * 6 + 3];
    const float op = opac[idx];
    const float u = -2.0f * y + 100.0f;   // sh = BEV_H/H_METERS = 2
    const float v = -2.0f * x + 100.0f;
    const float c00 = 4.0f * syy + 0.3f;
    const float c01 = 4.0f * sxy;
    const float c11 = 4.0f * sxx + 0.3f;
    const float det = c00 * c11 - c01 * c01;
    float4 bb = make_float4(1e9f, -1e9f, 1e9f, -1e9f);   // always-miss
    float qa = 0.f, qb = 0.f, qc = 0.f, lop = 0.f;
    if (op > 0.05f && det > 0.0f) {
        const float inv = 1.0f / det;
        qa = -0.5f * (c11 * inv);
        qb = c01 * inv;                  // == -cB
        qc = -0.5f * (c00 * inv);
        lop = logf(op);
        const float L = logf(255.0f * op);   // > 0 since op > 0.05
        const float ru = sqrtf(2.0f * L * c00) + 0.01f;
        const float rv = sqrtf(2.0f * L * c11) + 0.01f;
        bb = make_float4(u - ru, u + ru, v - rv, v + rv);
    }
    params[idx * 2 + 0] = make_float4(u, v, qa, qb);
    params[idx * 2 + 1] = make_float4(qc, lop, 0.0f, 0.0f);
    bbox[idx] = bb;
}

// round-to-nearest bf16 pack of two floats into one uint (lo=x, hi=y)
__device__ __forceinline__ unsigned pk2bf(float x, float y)
{
    unsigned ux = __float_as_uint(x), uy = __float_as_uint(y);
    ux = ux + 0x7fffu + ((ux >> 16) & 1u);
    uy = uy + 0x7fffu + ((uy >> 16) & 1u);
    return (ux >> 16) | (uy & 0xffff0000u);
}

// Phase 2: ONE WAVE per 8x8 tile — zero barriers end to end.
//   scan: streaming ballot compaction into slist (order-preserving).
//   stage: kept gaussians' params (fp32) + features (bf16-packed) into LDS
//          with independent parallel gathers.
//   composite: branchless, 6 LDS reads per gaussian (R5 had 10, and 2-wave
//   blocks doubled the shared-LDS-pipe issue traffic: ~7.8M chip cycles).
__global__ __launch_bounds__(64) void render_tile_kernel(
    const float* __restrict__ features, const float4* __restrict__ params,
    const float4* __restrict__ bbox, float* __restrict__ out, int G)
{
    __shared__ int slist[MAXG];
    __shared__ float4 plA[KC];   // u v qa qb
    __shared__ float2 plB[KC];   // qc lop
    __shared__ uint4 flq[KC][4]; // 32 bf16 features

    const int lane = threadIdx.x;
    const int b  = blockIdx.z;
    const int tj = blockIdx.x;
    const int ti = blockIdx.y;
    const int j = tj * TILE + (lane & 7);
    const int i = ti * TILE + (lane >> 3);
    const float fi = (float)i, fj = (float)j;
    const float ti_lo = (float)(ti * TILE), ti_hi = ti_lo + (TILE - 1);
    const float tj_lo = (float)(tj * TILE), tj_hi = tj_lo + (TILE - 1);
    const int gbase = b * G;

    // ---- scan: wave-private ballot compaction, no barriers ----
    int total = 0;
    for (int g0 = 0; g0 < G; g0 += 64) {
        const int g = g0 + lane;
        bool keep = false;
        if (g < G) {
            const float4 bb = bbox[gbase + g];
            keep = (bb.y >= ti_lo) && (bb.x <= ti_hi) &&
                   (bb.w >= tj_lo) && (bb.z <= tj_hi);
        }
        const unsigned long long bal = __ballot(keep);
        if (keep) {
            const int pre = (int)__popcll(bal & ((1ull << lane) - 1ull));
            slist[total + pre] = g;
        }
        total += (int)__popcll(bal);
    }

    // ---- chunked stage + branchless composite ----
    float acc[32];
#pragma unroll
    for (int d = 0; d < 32; ++d) acc[d] = 0.0f;
    float T = 1.0f;

    for (int k0 = 0; k0 < total; k0 += KC) {
        if (!__any(T >= T_DEAD)) break;
        const int nk = min(KC, total - k0);

        // stage params: one float4+float2 per kept entry
        if (lane < nk) {
            const int g = slist[k0 + lane];
            const float4* pp = params + (size_t)(gbase + g) * 2;
            const float4 a = pp[0];
            const float4 c = pp[1];
            plA[lane] = a;
            plB[lane] = make_float2(c.x, c.y);
        }
        // stage features: entry e, quarter q (8 floats -> 4 bf16-pairs)
        for (int idx = lane; idx < nk * 4; idx += 64) {
            const int e = idx >> 2, q = idx & 3;
            const int g = slist[k0 + e];
            const float4* fp =
                (const float4*)(features + (size_t)(gbase + g) * 32) + q * 2;
            const float4 A = fp[0], B = fp[1];
            flq[e][q] = make_uint4(pk2bf(A.x, A.y), pk2bf(A.z, A.w),
                                   pk2bf(B.x, B.y), pk2bf(B.z, B.w));
        }
        // same-wave LDS ordering: compiler inserts lgkmcnt waits

        for (int k = 0; k < nk; ++k) {
            const float4 pA = plA[k];
            const float2 pB = plB[k];
            const float du = pA.x - fi;
            const float dv = pA.y - fj;
            const float power = pA.z * du * du + pB.x * dv * dv + pA.w * du * dv;
            const float powb = power + pB.y;          // + ln(op)
            float alpha = fminf(0.99f, __expf(powb));
            const bool ok = (powb >= NLOG255) && (power <= 0.0f);  // NaN-safe: false
            alpha = ok ? alpha : 0.0f;
            const float w = alpha * T;
            T *= 1.0f - alpha;
#pragma unroll
            for (int q = 0; q < 4; ++q) {
                const uint4 uq = flq[k][q];
                const unsigned uu[4] = {uq.x, uq.y, uq.z, uq.w};
#pragma unroll
                for (int c = 0; c < 4; ++c) {
                    const float lo = __uint_as_float(uu[c] << 16);
                    const float hi = __uint_as_float(uu[c] & 0xffff0000u);
                    acc[q * 8 + c * 2 + 0] = fmaf(w, lo, acc[q * 8 + c * 2 + 0]);
                    acc[q * 8 + c * 2 + 1] = fmaf(w, hi, acc[q * 8 + c * 2 + 1]);
                }
            }
            if ((k & 7) == 7 && !__any(T >= T_DEAD)) break;
        }
    }

    const int p = i * BEV_W + j;   // 200 % 8 == 0: always in range
    float* ob = out + (size_t)b * 32 * NPIX + p;
#pragma unroll
    for (int d = 0; d < 32; ++d) ob[(size_t)d * NPIX] = acc[d];
}

// num_gaussians = sum(op > 0.05) / B
__global__ __launch_bounds__(256) void count_kernel(
    const float* __restrict__ opac, float* __restrict__ out, int n, int out_idx)
{
    __shared__ float sdata[256];
    const int tid = threadIdx.x;
    float s = 0.0f;
    for (int idx = tid; idx < n; idx += 256)
        s += (opac[idx] > 0.05f) ? 1.0f : 0.0f;
    sdata[tid] = s;
    __syncthreads();
    for (int off = 128; off > 0; off >>= 1) {
        if (tid < off) sdata[tid] += sdata[tid + off];
        __syncthreads();
    }
    if (tid == 0) out[out_idx] = sdata[0] * (1.0f / NB);
}

extern "C" void kernel_launch(void* const* d_in, const int* in_sizes, int n_in,
                              void* d_out, int out_size, void* d_ws, size_t ws_size,
                              hipStream_t stream)
{
    const float* features = (const float*)d_in[0];
    const float* means3D  = (const float*)d_in[1];
    const float* cov3D    = (const float*)d_in[2];
    const float* opac     = (const float*)d_in[3];
    float* out = (float*)d_out;

    const int G = in_sizes[3] / NB;   // opacities is (B, G, 1)
    const int n = NB * G;

    float4* params = (float4*)d_ws;           // n * 2 float4
    float4* bbox   = params + (size_t)n * 2;  // n float4

    precompute_kernel<<<(n + 255) / 256, 256, 0, stream>>>(
        means3D, cov3D, opac, params, bbox, n);

    dim3 grid(NT, NT, NB);
    render_tile_kernel<<<grid, 64, 0, stream>>>(features, params, bbox, out, G);

    count_kernel<<<1, 256, 0, stream>>>(opac, out, n, NB * 32 * NPIX);
}

// Round 7
// 92.009 us; speedup vs baseline: 1.1014x; 1.1014x over previous
//
#include <hip/hip_runtime.h>
#include <math.h>

#define BEV_H 200
#define BEV_W 200
#define NPIX (BEV_H * BEV_W)
#define TILE 8
#define NT 25           // 200/8
#define NB 2
#define T_DEAD 1e-10f
#define SEGCAP 512      // per-wave segment kept-list capacity (G/4 = 500)
#define KC 32           // kept-gaussian chunk staged in LDS per wave
#define NLOG255 (-5.5412635f)   // -ln(255)

// Phase 1: per-gaussian screen params + conservative bbox, once per gaussian.
// params[g*2+0] = (u, v, qa, qb); params[g*2+1] = (qc, ln(op), 0, 0)
// alpha = op*exp(power) = exp(power + ln op); alpha>=1/255 <=> powb >= -ln255
__global__ __launch_bounds__(256) void precompute_kernel(
    const float* __restrict__ means3D, const float* __restrict__ cov3D,
    const float* __restrict__ opac, float4* __restrict__ params,
    float4* __restrict__ bbox, int n /* NB*G */)
{
    const int idx = blockIdx.x * 256 + threadIdx.x;
    if (idx >= n) return;
    const float x = means3D[idx * 3 + 0], y = means3D[idx * 3 + 1];
    const float sxx = cov3D[idx * 6 + 0], sxy = cov3D[idx * 6 + 1],
                syy = cov3D[idx * 6 + 3];
    const float op = opac[idx];
    const float u = -2.0f * y + 100.0f;   // sh = BEV_H/H_METERS = 2
    const float v = -2.0f * x + 100.0f;
    const float c00 = 4.0f * syy + 0.3f;
    const float c01 = 4.0f * sxy;
    const float c11 = 4.0f * sxx + 0.3f;
    const float det = c00 * c11 - c01 * c01;
    float4 bb = make_float4(1e9f, -1e9f, 1e9f, -1e9f);   // always-miss
    float qa = 0.f, qb = 0.f, qc = 0.f, lop = 0.f;
    if (op > 0.05f && det > 0.0f) {
        const float inv = 1.0f / det;
        qa = -0.5f * (c11 * inv);
        qb = c01 * inv;                  // == -cB
        qc = -0.5f * (c00 * inv);
        lop = logf(op);
        const float L = logf(255.0f * op);   // > 0 since op > 0.05
        const float ru = sqrtf(2.0f * L * c00) + 0.01f;
        const float rv = sqrtf(2.0f * L * c11) + 0.01f;
        bb = make_float4(u - ru, u + ru, v - rv, v + rv);
    }
    params[idx * 2 + 0] = make_float4(u, v, qa, qb);
    params[idx * 2 + 1] = make_float4(qc, lop, 0.0f, 0.0f);
    bbox[idx] = bb;
}

// round-to-nearest bf16 pack of two floats into one uint (lo=x, hi=y)
__device__ __forceinline__ unsigned pk2bf(float x, float y)
{
    unsigned ux = __float_as_uint(x), uy = __float_as_uint(y);
    ux = ux + 0x7fffu + ((ux >> 16) & 1u);
    uy = uy + 0x7fffu + ((uy >> 16) & 1u);
    return (ux >> 16) | (uy & 0xffff0000u);
}

// Phase 2: 4 waves per 8x8 tile, G split into 4 segments (compositing monoid:
// out = a0 + T0*(a1 + T1*(a2 + T2*a3))). Each wave scans/stages/composites
// its segment WAVE-LOCALLY (no barriers; R5/R6 were latency-bound at ~1.2
// waves/SIMD with 4x longer serial chains). Hierarchical LDS combine at the
// end (3 barriers). Inner loop branchless + break-free => pipelinable.
__global__ __launch_bounds__(256) void render_tile_kernel(
    const float* __restrict__ features, const float4* __restrict__ params,
    const float4* __restrict__ bbox, float* __restrict__ out, int G)
{
    __shared__ int   slist[4][SEGCAP];
    __shared__ float4 plA[4][KC];        // u v qa qb
    __shared__ float2 plB[4][KC];        // qc ln(op)
    __shared__ uint4  flq[4][KC][4];     // 32 bf16 features
    __shared__ float  xch[2][64][33];    // acc[32] + T, stride 33 (bank rotate)

    const int tid  = threadIdx.x;
    const int lane = tid & 63;
    const int w    = tid >> 6;           // wave id = G-segment id
    const int b  = blockIdx.z;
    const int tj = blockIdx.x;
    const int ti = blockIdx.y;
    const int j = tj * TILE + (lane & 7);
    const int i = ti * TILE + (lane >> 3);
    const float fi = (float)i, fj = (float)j;
    const float ti_lo = (float)(ti * TILE), ti_hi = ti_lo + (TILE - 1);
    const float tj_lo = (float)(tj * TILE), tj_hi = tj_lo + (TILE - 1);
    const int gbase = b * G;

    const int g_lo = (w * G) >> 2;
    const int g_hi = ((w + 1) * G) >> 2;

    // ---- scan own segment: wave-local ballot compaction (order-preserving) ----
    int tot = 0;
    for (int g0 = g_lo; g0 < g_hi; g0 += 64) {
        const int g = g0 + lane;
        bool keep = false;
        if (g < g_hi) {
            const float4 bb = bbox[gbase + g];
            keep = (bb.y >= ti_lo) && (bb.x <= ti_hi) &&
                   (bb.w >= tj_lo) && (bb.z <= tj_hi);
        }
        const unsigned long long bal = __ballot(keep);
        if (keep) {
            const int pre = (int)__popcll(bal & ((1ull << lane) - 1ull));
            slist[w][tot + pre] = g;
        }
        tot += (int)__popcll(bal);
    }

    // ---- wave-local chunked stage + branchless composite ----
    float acc[32];
#pragma unroll
    for (int d = 0; d < 32; ++d) acc[d] = 0.0f;
    float T = 1.0f;   // within-segment transmittance

    for (int k0 = 0; k0 < tot; k0 += KC) {
        if (!__any(T >= T_DEAD)) break;   // segment-local exit is exact enough
        const int nk = min(KC, tot - k0);

        if (lane < nk) {
            const int g = slist[w][k0 + lane];
            const float4* pp = params + (size_t)(gbase + g) * 2;
            const float4 a = pp[0];
            const float4 c = pp[1];
            plA[w][lane] = a;
            plB[w][lane] = make_float2(c.x, c.y);
        }
        for (int idx = lane; idx < nk * 4; idx += 64) {
            const int e = idx >> 2, q = idx & 3;
            const int g = slist[w][k0 + e];
            const float4* fp =
                (const float4*)(features + (size_t)(gbase + g) * 32) + q * 2;
            const float4 A = fp[0], B = fp[1];
            flq[w][e][q] = make_uint4(pk2bf(A.x, A.y), pk2bf(A.z, A.w),
                                      pk2bf(B.x, B.y), pk2bf(B.z, B.w));
        }
        // same-wave LDS ordering: lgkmcnt waits inserted by compiler

#pragma unroll 2
        for (int k = 0; k < nk; ++k) {
            const float4 pA = plA[w][k];
            const float2 pB = plB[w][k];
            const float du = pA.x - fi;
            const float dv = pA.y - fj;
            const float power = pA.z * du * du + pB.x * dv * dv + pA.w * du * dv;
            const float powb = power + pB.y;          // + ln(op)
            float alpha = fminf(0.99f, __expf(powb));
            const bool ok = (powb >= NLOG255) && (power <= 0.0f);
            alpha = ok ? alpha : 0.0f;
            const float wgt = alpha * T;
            T *= 1.0f - alpha;
#pragma unroll
            for (int q = 0; q < 4; ++q) {
                const uint4 uq = flq[w][k][q];
                const unsigned uu[4] = {uq.x, uq.y, uq.z, uq.w};
#pragma unroll
                for (int c = 0; c < 4; ++c) {
                    const float lo = __uint_as_float(uu[c] << 16);
                    const float hi = __uint_as_float(uu[c] & 0xffff0000u);
                    acc[q * 8 + c * 2 + 0] = fmaf(wgt, lo, acc[q * 8 + c * 2 + 0]);
                    acc[q * 8 + c * 2 + 1] = fmaf(wgt, hi, acc[q * 8 + c * 2 + 1]);
                }
            }
        }
    }

    // ---- hierarchical combine: (w0<-w1), (w2<-w3), then (w0<-w2) ----
    if (w == 1 || w == 3) {
        float* row = xch[(w - 1) >> 1][lane];
#pragma unroll
        for (int d = 0; d < 32; ++d) row[d] = acc[d];
        row[32] = T;
    }
    __syncthreads();
    if (w == 0 || w == 2) {
        const float* row = xch[w >> 1][lane];
        const float Tn = row[32];
#pragma unroll
        for (int d = 0; d < 32; ++d) acc[d] = fmaf(T, row[d], acc[d]);
        T *= Tn;
    }
    __syncthreads();
    if (w == 2) {
        float* row = xch[0][lane];
#pragma unroll
        for (int d = 0; d < 32; ++d) row[d] = acc[d];
        row[32] = T;
    }
    __syncthreads();
    if (w == 0) {
        const float* row = xch[0][lane];
#pragma unroll
        for (int d = 0; d < 32; ++d) acc[d] = fmaf(T, row[d], acc[d]);

        const int p = i * BEV_W + j;   // 200 % 8 == 0: always in range
        float* ob = out + (size_t)b * 32 * NPIX + p;
#pragma unroll
        for (int d = 0; d < 32; ++d) ob[(size_t)d * NPIX] = acc[d];
    }
}

// num_gaussians = sum(op > 0.05) / B
__global__ __launch_bounds__(256) void count_kernel(
    const float* __restrict__ opac, float* __restrict__ out, int n, int out_idx)
{
    __shared__ float sdata[256];
    const int tid = threadIdx.x;
    float s = 0.0f;
    for (int idx = tid; idx < n; idx += 256)
        s += (opac[idx] > 0.05f) ? 1.0f : 0.0f;
    sdata[tid] = s;
    __syncthreads();
    for (int off = 128; off > 0; off >>= 1) {
        if (tid < off) sdata[tid] += sdata[tid + off];
        __syncthreads();
    }
    if (tid == 0) out[out_idx] = sdata[0] * (1.0f / NB);
}

extern "C" void kernel_launch(void* const* d_in, const int* in_sizes, int n_in,
                              void* d_out, int out_size, void* d_ws, size_t ws_size,
                              hipStream_t stream)
{
    const float* features = (const float*)d_in[0];
    const float* means3D  = (const float*)d_in[1];
    const float* cov3D    = (const float*)d_in[2];
    const float* opac     = (const float*)d_in[3];
    float* out = (float*)d_out;

    const int G = in_sizes[3] / NB;   // opacities is (B, G, 1)
    const int n = NB * G;

    float4* params = (float4*)d_ws;           // n * 2 float4
    float4* bbox   = params + (size_t)n * 2;  // n float4

    precompute_kernel<<<(n + 255) / 256, 256, 0, stream>>>(
        means3D, cov3D, opac, params, bbox, n);

    dim3 grid(NT, NT, NB);
    render_tile_kernel<<<grid, 256, 0, stream>>>(features, params, bbox, out, G);

    count_kernel<<<1, 256, 0, stream>>>(opac, out, n, NB * 32 * NPIX);
}

// Round 8
// 84.006 us; speedup vs baseline: 1.2063x; 1.0953x over previous
//
#include <hip/hip_runtime.h>
#include <math.h>

#define BEV_H 200
#define BEV_W 200
#define NPIX (BEV_H * BEV_W)
#define TILE 8
#define NT 25           // 200/8
#define NB 2
#define T_DEAD 1e-10f
#define SEGCAP 512      // per-wave segment capacity (G/4 = 500)
#define KC 32           // kept-gaussian chunk staged in LDS per wave
#define NLOG255 (-5.5412635f)   // -ln(255)

// round-to-nearest bf16 pack of two floats into one uint (lo=x, hi=y)
__device__ __forceinline__ unsigned pk2bf(float x, float y)
{
    unsigned ux = __float_as_uint(x), uy = __float_as_uint(y);
    ux = ux + 0x7fffu + ((ux >> 16) & 1u);
    uy = uy + 0x7fffu + ((uy >> 16) & 1u);
    return (ux >> 16) | (uy & 0xffff0000u);
}

// SINGLE fused kernel. 4 waves per 8x8 tile; G split in 4 segments
// (compositing monoid: out = a0 + T0*(a1 + T1*(a2 + T2*a3))).
// - scan: inline precompute (no separate kernel, no ws round-trip, no
//   cross-dispatch dependency — R7 paid 3 dependent dispatches on caches
//   freshly evicted by the harness's 256 MiB poison fill each iteration),
//   2-deep load pipeline, wave-local ballot compaction.
// - stage: params recomputed from inputs for the ~11 kept/wave; features
//   packed to bf16 in LDS.
// - composite: branchless, break-free inner loop (pipelinable ds_reads).
// - combine: hierarchical in-LDS (3 barriers); count folded into block 0.
__global__ __launch_bounds__(256) void render_fused_kernel(
    const float* __restrict__ features, const float* __restrict__ means3D,
    const float* __restrict__ cov3D, const float* __restrict__ opac,
    float* __restrict__ out, int G)
{
    __shared__ int    glist[4][SEGCAP];
    __shared__ float4 plA[4][KC];        // u v qa qb
    __shared__ float2 plB[4][KC];        // qc ln(op)
    __shared__ uint4  flq[4][KC][4];     // 32 bf16 features
    __shared__ float  xch[2][64][33];    // acc[32]+T exchange, stride 33

    const int tid  = threadIdx.x;
    const int lane = tid & 63;
    const int w    = tid >> 6;           // wave id = G-segment id
    const int b  = blockIdx.z;
    const int tj = blockIdx.x;
    const int ti = blockIdx.y;
    const int j = tj * TILE + (lane & 7);
    const int i = ti * TILE + (lane >> 3);
    const float fi = (float)i, fj = (float)j;
    const float ti_lo = (float)(ti * TILE), ti_hi = ti_lo + (TILE - 1);
    const float tj_lo = (float)(tj * TILE), tj_hi = tj_lo + (TILE - 1);
    const int gbase = b * G;
    const int g_lo = (w * G) >> 2;
    const int g_hi = ((w + 1) * G) >> 2;
    const int rounds = (g_hi - g_lo + 63) >> 6;

    // ---- scan: inline precompute, 2-deep pipelined loads, ballot compact ----
    int tot = 0;
    {
        int gg = min(g_lo + lane, g_hi - 1);
        size_t gi = (size_t)(gbase + gg);
        float x0 = means3D[gi * 3 + 0], y0 = means3D[gi * 3 + 1];
        float s0 = cov3D[gi * 6 + 0], s1 = cov3D[gi * 6 + 1], s3 = cov3D[gi * 6 + 3];
        float o0 = opac[gi];
        for (int r = 0; r < rounds; ++r) {
            float x1 = 0.f, y1 = 0.f, t0 = 0.f, t1 = 0.f, t3 = 0.f, o1 = 0.f;
            if (r + 1 < rounds) {   // prefetch next round (wave-uniform branch)
                const int gn = min(g_lo + (r + 1) * 64 + lane, g_hi - 1);
                const size_t gni = (size_t)(gbase + gn);
                x1 = means3D[gni * 3 + 0]; y1 = means3D[gni * 3 + 1];
                t0 = cov3D[gni * 6 + 0];   t1 = cov3D[gni * 6 + 1];
                t3 = cov3D[gni * 6 + 3];   o1 = opac[gni];
            }
            const int g = g_lo + r * 64 + lane;
            const float u = -2.0f * y0 + 100.0f;   // sh = BEV_H/H_METERS = 2
            const float v = -2.0f * x0 + 100.0f;
            const float c00 = 4.0f * s3 + 0.3f;
            const float c01 = 4.0f * s1;
            const float c11 = 4.0f * s0 + 0.3f;
            const float det = c00 * c11 - c01 * c01;
            bool keep = false;
            if (o0 > 0.05f && det > 0.0f && g < g_hi) {
                const float L = __logf(255.0f * o0);   // > 0 since op > 0.05
                const float ru = sqrtf(2.0f * L * c00) + 0.01f;
                const float rv = sqrtf(2.0f * L * c11) + 0.01f;
                keep = (u + ru >= ti_lo) && (u - ru <= ti_hi) &&
                       (v + rv >= tj_lo) && (v - rv <= tj_hi);
            }
            const unsigned long long bal = __ballot(keep);
            if (keep) {
                const int pre = (int)__popcll(bal & ((1ull << lane) - 1ull));
                glist[w][tot + pre] = g;
            }
            tot += (int)__popcll(bal);
            x0 = x1; y0 = y1; s0 = t0; s1 = t1; s3 = t3; o0 = o1;
        }
    }

    // ---- wave-local chunked stage + branchless composite ----
    float acc[32];
#pragma unroll
    for (int d = 0; d < 32; ++d) acc[d] = 0.0f;
    float T = 1.0f;   // within-segment transmittance

    for (int k0 = 0; k0 < tot; k0 += KC) {
        if (!__any(T >= T_DEAD)) break;
        const int nk = min(KC, tot - k0);

        // stage params: recompute from inputs for kept entries only
        if (lane < nk) {
            const int g = glist[w][k0 + lane];
            const size_t gi = (size_t)(gbase + g);
            const float x = means3D[gi * 3 + 0], y = means3D[gi * 3 + 1];
            const float sxx = cov3D[gi * 6 + 0], sxy = cov3D[gi * 6 + 1],
                        syy = cov3D[gi * 6 + 3];
            const float op = opac[gi];
            const float u = -2.0f * y + 100.0f;
            const float v = -2.0f * x + 100.0f;
            const float c00 = 4.0f * syy + 0.3f;
            const float c01 = 4.0f * sxy;
            const float c11 = 4.0f * sxx + 0.3f;
            const float inv = 1.0f / (c00 * c11 - c01 * c01);  // det>0: was kept
            plA[w][lane] = make_float4(u, v, -0.5f * c11 * inv, c01 * inv);
            plB[w][lane] = make_float2(-0.5f * c00 * inv, __logf(op));
        }
        // stage features: entry e, quarter q (8 floats -> 4 bf16-pairs)
        for (int idx = lane; idx < nk * 4; idx += 64) {
            const int e = idx >> 2, q = idx & 3;
            const int g = glist[w][k0 + e];
            const float4* fp =
                (const float4*)(features + (size_t)(gbase + g) * 32) + q * 2;
            const float4 A = fp[0], Bq = fp[1];
            flq[w][e][q] = make_uint4(pk2bf(A.x, A.y), pk2bf(A.z, A.w),
                                      pk2bf(Bq.x, Bq.y), pk2bf(Bq.z, Bq.w));
        }
        // same-wave LDS ordering: compiler inserts lgkmcnt waits

#pragma unroll 2
        for (int k = 0; k < nk; ++k) {
            const float4 pA = plA[w][k];
            const float2 pB = plB[w][k];
            const float du = pA.x - fi;
            const float dv = pA.y - fj;
            const float power = pA.z * du * du + pB.x * dv * dv + pA.w * du * dv;
            const float powb = power + pB.y;          // + ln(op)
            float alpha = fminf(0.99f, __expf(powb));
            const bool ok = (powb >= NLOG255) && (power <= 0.0f);
            alpha = ok ? alpha : 0.0f;
            const float wgt = alpha * T;
            T *= 1.0f - alpha;
#pragma unroll
            for (int q = 0; q < 4; ++q) {
                const uint4 uq = flq[w][k][q];
                const unsigned uu[4] = {uq.x, uq.y, uq.z, uq.w};
#pragma unroll
                for (int c = 0; c < 4; ++c) {
                    const float lo = __uint_as_float(uu[c] << 16);
                    const float hi = __uint_as_float(uu[c] & 0xffff0000u);
                    acc[q * 8 + c * 2 + 0] = fmaf(wgt, lo, acc[q * 8 + c * 2 + 0]);
                    acc[q * 8 + c * 2 + 1] = fmaf(wgt, hi, acc[q * 8 + c * 2 + 1]);
                }
            }
        }
    }

    // ---- hierarchical combine: (w0<-w1), (w2<-w3), then (w0<-w2) ----
    if (w == 1 || w == 3) {
        float* row = xch[(w - 1) >> 1][lane];
#pragma unroll
        for (int d = 0; d < 32; ++d) row[d] = acc[d];
        row[32] = T;
    }
    __syncthreads();
    if (w == 0 || w == 2) {
        const float* row = xch[w >> 1][lane];
        const float Tn = row[32];
#pragma unroll
        for (int d = 0; d < 32; ++d) acc[d] = fmaf(T, row[d], acc[d]);
        T *= Tn;
    }
    __syncthreads();
    if (w == 2) {
        float* row = xch[0][lane];
#pragma unroll
        for (int d = 0; d < 32; ++d) row[d] = acc[d];
        row[32] = T;
    }
    __syncthreads();

    if (w == 0) {
        const float* row = xch[0][lane];
#pragma unroll
        for (int d = 0; d < 32; ++d) acc[d] = fmaf(T, row[d], acc[d]);

        const int p = i * BEV_W + j;   // 200 % 8 == 0: always in range
        float* ob = out + (size_t)b * 32 * NPIX + p;
#pragma unroll
        for (int d = 0; d < 32; ++d) ob[(size_t)d * NPIX] = acc[d];
    }

    // ---- num_gaussians = sum(op > 0.05)/B, on block 0 wave 1 (post-barrier,
    //      overlapped with the rest of the grid) ----
    if (w == 1 && blockIdx.x == 0 && blockIdx.y == 0 && blockIdx.z == 0) {
        const float4* o4 = (const float4*)opac;
        const int n4 = (NB * G) >> 2;   // 4000/4, G=2000
        float s = 0.0f;
        for (int idx = lane; idx < n4; idx += 64) {
            const float4 o = o4[idx];
            s += (o.x > 0.05f ? 1.0f : 0.0f) + (o.y > 0.05f ? 1.0f : 0.0f) +
                 (o.z > 0.05f ? 1.0f : 0.0f) + (o.w > 0.05f ? 1.0f : 0.0f);
        }
#pragma unroll
        for (int off = 32; off > 0; off >>= 1) s += __shfl_down(s, off);
        if (lane == 0) out[NB * 32 * NPIX] = s * (1.0f / NB);
    }
}

extern "C" void kernel_launch(void* const* d_in, const int* in_sizes, int n_in,
                              void* d_out, int out_size, void* d_ws, size_t ws_size,
                              hipStream_t stream)
{
    const float* features = (const float*)d_in[0];
    const float* means3D  = (const float*)d_in[1];
    const float* cov3D    = (const float*)d_in[2];
    const float* opac     = (const float*)d_in[3];
    float* out = (float*)d_out;

    const int G = in_sizes[3] / NB;   // opacities is (B, G, 1)

    dim3 grid(NT, NT, NB);
    render_fused_kernel<<<grid, 256, 0, stream>>>(features, means3D, cov3D, opac,
                                                  out, G);
}

// Round 9
// 82.445 us; speedup vs baseline: 1.2292x; 1.0189x over previous
//
#include <hip/hip_runtime.h>
#include <math.h>

#define BEV_H 200
#define BEV_W 200
#define NPIX (BEV_H * BEV_W)
#define TILE 8
#define NT 25           // 200/8
#define NB 2
#define T_DEAD 1e-10f
#define SEGCAP 512      // per-wave segment capacity (G/4 = 500)
#define PCAP 128        // params parked at scan time (multiple of KC)
#define KC 32           // feature-staging chunk per wave
#define NLOG255 (-5.5412635f)   // -ln(255)

// round-to-nearest bf16 pack of two floats into one uint (lo=x, hi=y)
__device__ __forceinline__ unsigned pk2bf(float x, float y)
{
    unsigned ux = __float_as_uint(x), uy = __float_as_uint(y);
    ux = ux + 0x7fffu + ((ux >> 16) & 1u);
    uy = uy + 0x7fffu + ((uy >> 16) & 1u);
    return (ux >> 16) | (uy & 0xffff0000u);
}

// Fused renderer, R9: 4 waves per 8x8 tile, G in 4 segments (compositing
// monoid). vs R8:
//  - params parked in LDS AT SCAN TIME (registers already hold them at the
//    ballot) -> stage phase gathers features only: ONE cold-miss phase, no
//    recompute round-trip.
//  - LDS 36.4 -> 24 KB (ushort glist; combine-exchange overlays scan
//    buffers) + launch_bounds(256,5): whole 1250-block grid co-resident
//    (R8 ran in 2+ generations at 4 blocks/CU).
__global__ __launch_bounds__(256, 5) void render_fused_kernel(
    const float* __restrict__ features, const float* __restrict__ means3D,
    const float* __restrict__ cov3D, const float* __restrict__ opac,
    float* __restrict__ out, int G)
{
    // scan/composite layout: glist u16[4][512] | plA f4[4][128] |
    //   plB f2[4][128] | flq u4[4][32][4]  = 24576 B
    // combine overlay (after a barrier): xch f32[2][64][33] = 16896 B
    __shared__ __align__(16) unsigned char smem[24576];
    unsigned short* glist = (unsigned short*)smem;            // [4][512]
    float4* plA = (float4*)(smem + 4096);                     // [4][128]
    float2* plB = (float2*)(smem + 12288);                    // [4][128]
    uint4*  flq = (uint4*)(smem + 16384);                     // [4][32][4]
    float*  xch = (float*)smem;                               // [2][64][33]

    const int tid  = threadIdx.x;
    const int lane = tid & 63;
    const int w    = tid >> 6;           // wave id = G-segment id
    const int b  = blockIdx.z;
    const int tj = blockIdx.x;
    const int ti = blockIdx.y;
    const int j = tj * TILE + (lane & 7);
    const int i = ti * TILE + (lane >> 3);
    const float fi = (float)i, fj = (float)j;
    const float ti_lo = (float)(ti * TILE), ti_hi = ti_lo + (TILE - 1);
    const float tj_lo = (float)(tj * TILE), tj_hi = tj_lo + (TILE - 1);
    const int gbase = b * G;
    const int g_lo = (w * G) >> 2;
    const int g_hi = ((w + 1) * G) >> 2;
    const int rounds = (g_hi - g_lo + 63) >> 6;

    // ---- scan: inline precompute, 2-deep pipelined loads, ballot compact,
    //      params parked into LDS directly from registers ----
    int tot = 0;
    {
        int gg = min(g_lo + lane, g_hi - 1);
        size_t gi = (size_t)(gbase + gg);
        float x0 = means3D[gi * 3 + 0], y0 = means3D[gi * 3 + 1];
        float s0 = cov3D[gi * 6 + 0], s1 = cov3D[gi * 6 + 1], s3 = cov3D[gi * 6 + 3];
        float o0 = opac[gi];
        for (int r = 0; r < rounds; ++r) {
            float x1 = 0.f, y1 = 0.f, t0 = 0.f, t1 = 0.f, t3 = 0.f, o1 = 0.f;
            if (r + 1 < rounds) {   // prefetch next round (wave-uniform branch)
                const int gn = min(g_lo + (r + 1) * 64 + lane, g_hi - 1);
                const size_t gni = (size_t)(gbase + gn);
                x1 = means3D[gni * 3 + 0]; y1 = means3D[gni * 3 + 1];
                t0 = cov3D[gni * 6 + 0];   t1 = cov3D[gni * 6 + 1];
                t3 = cov3D[gni * 6 + 3];   o1 = opac[gni];
            }
            const int g = g_lo + r * 64 + lane;
            const float u = -2.0f * y0 + 100.0f;   // sh = BEV_H/H_METERS = 2
            const float v = -2.0f * x0 + 100.0f;
            const float c00 = 4.0f * s3 + 0.3f;
            const float c01 = 4.0f * s1;
            const float c11 = 4.0f * s0 + 0.3f;
            const float det = c00 * c11 - c01 * c01;
            bool keep = false;
            float L = 0.0f;
            if (o0 > 0.05f && det > 0.0f && g < g_hi) {
                L = __logf(255.0f * o0);           // > 0 since op > 0.05
                const float ru = sqrtf(2.0f * L * c00) + 0.01f;
                const float rv = sqrtf(2.0f * L * c11) + 0.01f;
                keep = (u + ru >= ti_lo) && (u - ru <= ti_hi) &&
                       (v + rv >= tj_lo) && (v - rv <= tj_hi);
            }
            const unsigned long long bal = __ballot(keep);
            if (keep) {
                const int slot = tot + (int)__popcll(bal & ((1ull << lane) - 1ull));
                glist[w * SEGCAP + slot] = (unsigned short)g;
                if (slot < PCAP) {
                    const float inv = 1.0f / det;
                    plA[w * PCAP + slot] =
                        make_float4(u, v, -0.5f * c11 * inv, c01 * inv);
                    // ln(op) = L - ln255
                    plB[w * PCAP + slot] = make_float2(-0.5f * c00 * inv,
                                                       L + NLOG255);
                }
            }
            tot += (int)__popcll(bal);
            x0 = x1; y0 = y1; s0 = t0; s1 = t1; s3 = t3; o0 = o1;
        }
    }

    // ---- wave-local: stage features per chunk + branchless composite ----
    float acc[32];
#pragma unroll
    for (int d = 0; d < 32; ++d) acc[d] = 0.0f;
    float T = 1.0f;   // within-segment transmittance

    for (int k0 = 0; k0 < tot; k0 += KC) {
        if (!__any(T >= T_DEAD)) break;
        const int nk = min(KC, tot - k0);

        // overflow chunks (k0 >= PCAP, ~never at ~11 kept/wave): recompute
        // params into slots [0,KC) (long since consumed)
        if (k0 >= PCAP && lane < nk) {
            const int g = glist[w * SEGCAP + k0 + lane];
            const size_t gi = (size_t)(gbase + g);
            const float x = means3D[gi * 3 + 0], y = means3D[gi * 3 + 1];
            const float sxx = cov3D[gi * 6 + 0], sxy = cov3D[gi * 6 + 1],
                        syy = cov3D[gi * 6 + 3];
            const float op = opac[gi];
            const float u = -2.0f * y + 100.0f;
            const float v = -2.0f * x + 100.0f;
            const float c00 = 4.0f * syy + 0.3f;
            const float c01 = 4.0f * sxy;
            const float c11 = 4.0f * sxx + 0.3f;
            const float inv = 1.0f / (c00 * c11 - c01 * c01);
            plA[w * PCAP + lane] = make_float4(u, v, -0.5f * c11 * inv, c01 * inv);
            plB[w * PCAP + lane] = make_float2(-0.5f * c00 * inv, __logf(op));
        }
        // stage features: entry e, quarter q (8 floats -> 4 bf16-pairs)
        for (int idx = lane; idx < nk * 4; idx += 64) {
            const int e = idx >> 2, q = idx & 3;
            const int g = glist[w * SEGCAP + k0 + e];
            const float4* fp =
                (const float4*)(features + (size_t)(gbase + g) * 32) + q * 2;
            const float4 A = fp[0], Bq = fp[1];
            flq[(w * KC + e) * 4 + q] = make_uint4(pk2bf(A.x, A.y), pk2bf(A.z, A.w),
                                                   pk2bf(Bq.x, Bq.y), pk2bf(Bq.z, Bq.w));
        }
        // same-wave LDS ordering: compiler inserts lgkmcnt waits

        const int pbase = w * PCAP + ((k0 < PCAP) ? k0 : 0);
        for (int k = 0; k < nk; ++k) {
            const float4 pA = plA[pbase + k];
            const float2 pB = plB[pbase + k];
            const float du = pA.x - fi;
            const float dv = pA.y - fj;
            const float power = pA.z * du * du + pB.x * dv * dv + pA.w * du * dv;
            const float powb = power + pB.y;          // + ln(op)
            float alpha = fminf(0.99f, __expf(powb));
            const bool ok = (powb >= NLOG255) && (power <= 0.0f);
            alpha = ok ? alpha : 0.0f;
            const float wgt = alpha * T;
            T *= 1.0f - alpha;
#pragma unroll
            for (int q = 0; q < 4; ++q) {
                const uint4 uq = flq[(w * KC + k) * 4 + q];
                const unsigned uu[4] = {uq.x, uq.y, uq.z, uq.w};
#pragma unroll
                for (int c = 0; c < 4; ++c) {
                    const float lo = __uint_as_float(uu[c] << 16);
                    const float hi = __uint_as_float(uu[c] & 0xffff0000u);
                    acc[q * 8 + c * 2 + 0] = fmaf(wgt, lo, acc[q * 8 + c * 2 + 0]);
                    acc[q * 8 + c * 2 + 1] = fmaf(wgt, hi, acc[q * 8 + c * 2 + 1]);
                }
            }
        }
    }

    // ---- combine: overlay xch on scan buffers (guarded by barrier) ----
    __syncthreads();   // all waves done with glist/plA/plB/flq
    if (w == 1 || w == 3) {
        float* row = xch + (((w - 1) >> 1) * 64 + lane) * 33;
#pragma unroll
        for (int d = 0; d < 32; ++d) row[d] = acc[d];
        row[32] = T;
    }
    __syncthreads();
    if (w == 0 || w == 2) {
        const float* row = xch + ((w >> 1) * 64 + lane) * 33;
        const float Tn = row[32];
#pragma unroll
        for (int d = 0; d < 32; ++d) acc[d] = fmaf(T, row[d], acc[d]);
        T *= Tn;
    }
    __syncthreads();
    if (w == 2) {
        float* row = xch + lane * 33;
#pragma unroll
        for (int d = 0; d < 32; ++d) row[d] = acc[d];
        row[32] = T;
    }
    __syncthreads();

    if (w == 0) {
        const float* row = xch + lane * 33;
#pragma unroll
        for (int d = 0; d < 32; ++d) acc[d] = fmaf(T, row[d], acc[d]);

        const int p = i * BEV_W + j;   // 200 % 8 == 0: always in range
        float* ob = out + (size_t)b * 32 * NPIX + p;
#pragma unroll
        for (int d = 0; d < 32; ++d) ob[(size_t)d * NPIX] = acc[d];
    }

    // ---- num_gaussians = sum(op > 0.05)/B on block 0 wave 1 (hidden tail) ----
    if (w == 1 && blockIdx.x == 0 && blockIdx.y == 0 && blockIdx.z == 0) {
        const float4* o4 = (const float4*)opac;
        const int n4 = (NB * G) >> 2;
        float s = 0.0f;
        for (int idx = lane; idx < n4; idx += 64) {
            const float4 o = o4[idx];
            s += (o.x > 0.05f ? 1.0f : 0.0f) + (o.y > 0.05f ? 1.0f : 0.0f) +
                 (o.z > 0.05f ? 1.0f : 0.0f) + (o.w > 0.05f ? 1.0f : 0.0f);
        }
#pragma unroll
        for (int off = 32; off > 0; off >>= 1) s += __shfl_down(s, off);
        if (lane == 0) out[NB * 32 * NPIX] = s * (1.0f / NB);
    }
}

extern "C" void kernel_launch(void* const* d_in, const int* in_sizes, int n_in,
                              void* d_out, int out_size, void* d_ws, size_t ws_size,
                              hipStream_t stream)
{
    const float* features = (const float*)d_in[0];
    const float* means3D  = (const float*)d_in[1];
    const float* cov3D    = (const float*)d_in[2];
    const float* opac     = (const float*)d_in[3];
    float* out = (float*)d_out;

    const int G = in_sizes[3] / NB;   // opacities is (B, G, 1)

    dim3 grid(NT, NT, NB);
    render_fused_kernel<<<grid, 256, 0, stream>>>(features, means3D, cov3D, opac,
                                                  out, G);
}